// Round 12
// baseline (941.613 us; speedup 1.0000x reference)
//
#include <hip/hip_runtime.h>
#include <hip/hip_fp16.h>
#include <math.h>

#define DEVINL __device__ __forceinline__

// ---------------------------------------------------------------------------
// SplineCNN net, round 11: round-8 structure + fdot2 inner loop with ZERO
// per-thread arrays (both operands read from LDS each iteration).
//  - x transposed in LDS ([i2][row], pad) -> RT rows = one ds_read_b64;
//    W as fp16 cin-pairs -> one broadcast ds_read_b128 per (corner,i2).
//  - corners outer, t4[RT] accumulator, ws applied once per corner.
//  - rounds 9/10 both spilled via register x-preload arrays (rule #20);
//    this formulation has no arrays to spill.
// ---------------------------------------------------------------------------

typedef _Float16 h2t __attribute__((ext_vector_type(2)));

DEVINL unsigned f2mono(float f) {
    unsigned u = __float_as_uint(f);
    return (u & 0x80000000u) ? ~u : (u | 0x80000000u);
}
DEVINL float mono2x(unsigned m) {  // sentinel 0 == empty segment -> 0.0
    if (m == 0u) return 0.f;
    unsigned u = (m & 0x80000000u) ? (m & 0x7FFFFFFFu) : ~m;
    return __uint_as_float(u);
}
DEVINL unsigned short f2h(float f) {
    union { __half h; unsigned short u; } c;
    c.h = __float2half_rn(f);
    return c.u;
}
DEVINL float h2f(unsigned short s) {
    union { unsigned short u; __half h; } c;
    c.u = s;
    return __half2float(c.h);
}
DEVINL float fdot2u(unsigned w, unsigned x, float acc) {
    union { unsigned u; h2t h; } cw, cx;
    cw.u = w;
    cx.u = x;
    return __builtin_amdgcn_fdot2(cw.h, cx.h, acc, false);
}

__global__ void fill_u32(unsigned* __restrict__ p, int n, unsigned v) {
    int i = blockIdx.x * blockDim.x + threadIdx.x;
    if (i < n) p[i] = v;
}

DEVINL void decode3(float p0, float p1, float p2, int ff[3], float fr[3]) {
    float pp[3] = {p0 * 4.f, p1 * 4.f, p2 * 4.f};  // (K-1) = 4
#pragma unroll
    for (int d = 0; d < 3; ++d) {
        int fi = (int)floorf(pp[d]);
        fi = fi < 0 ? 0 : (fi > 4 ? 4 : fi);
        ff[d] = fi;
        fr[d] = pp[d] - (float)fi;
    }
}
DEVINL void pseudo_decode(const float* __restrict__ ps, int e, int ff[3], float fr[3]) {
    decode3(ps[(size_t)e * 3], ps[(size_t)e * 3 + 1], ps[(size_t)e * 3 + 2], ff, fr);
}

DEVINL void corner_iw(const int ff[3], const float fr[3], int bits, float& w, int& idx) {
    w = 1.f;
    idx = 0;
    int pw = 1;
#pragma unroll
    for (int d = 0; d < 3; ++d) {
        int b = (bits >> d) & 1;
        w *= b ? fr[d] : (1.f - fr[d]);
        int fd = ff[d] + b;
        fd = fd < 0 ? 0 : (fd > 4 ? 4 : fd);
        idx += fd * pw;
        pw *= 5;
    }
}

// ---------------- batched hist (cell id, L2-5) + deg (all) + pool0 -----------
DEVINL void hist_seg(const float* __restrict__ ps, const int* __restrict__ dst, int E,
                     int* __restrict__ hist, int* __restrict__ ideg, int bofs, int t,
                     int* __restrict__ lh) {
    for (int i = t; i < 125; i += 256) lh[i] = 0;
    __syncthreads();
    int e = bofs * 256 + t;
    if (e < E) {
        int ff[3];
        float fr[3];
        pseudo_decode(ps, e, ff, fr);
        int cid = ff[0] + 5 * ff[1] + 25 * ff[2];
        atomicAdd(&lh[cid], 1);
        atomicAdd(&ideg[dst[e]], 1);
    }
    __syncthreads();
    for (int i = t; i < 125; i += 256)
        if (lh[i]) atomicAdd(&hist[i], lh[i]);
}

__global__ void hist_all(const float* ps2, const int* dst2, int E2, int* hist2, int* ideg2,
                         const float* ps3, const int* dst3, int E3, int* hist3, int* ideg3,
                         const float* ps4, const int* dst4, int E4, int* hist4, int* ideg4,
                         const float* ps5, const int* dst5, int E5, int* hist5, int* ideg5,
                         const int* dst1, int E1, int* ideg1, const float* x0, const int* cl1,
                         int n0, unsigned* xp1m, int B2, int B23, int B234, int B2345,
                         int B1end) {
    __shared__ int lh[125];
    int b = blockIdx.x, t = threadIdx.x;
    if (b < B2) hist_seg(ps2, dst2, E2, hist2, ideg2, b, t, lh);
    else if (b < B23) hist_seg(ps3, dst3, E3, hist3, ideg3, b - B2, t, lh);
    else if (b < B234) hist_seg(ps4, dst4, E4, hist4, ideg4, b - B23, t, lh);
    else if (b < B2345) hist_seg(ps5, dst5, E5, hist5, ideg5, b - B234, t, lh);
    else if (b < B1end) {
        int e = (b - B2345) * 256 + t;
        if (e < E1) atomicAdd(&ideg1[dst1[e]], 1);
    } else {
        int i = (b - B1end) * 256 + t;
        if (i < n0) atomicMax(&xp1m[cl1[i]], f2mono(x0[i]));
    }
}

// ---------------- claims + bin-prefixes (wave-parallel) ----------------------
DEVINL void claim_seg(const int* __restrict__ cnt, int N, int* __restrict__ gcur,
                      int* __restrict__ ebase, int* __restrict__ cur, int bofs, int t) {
    int i = bofs * 256 + t;
    int lane = t & 63;
    int v = (i < N) ? cnt[i] : 0;
    int s = v;
#pragma unroll
    for (int st = 1; st < 64; st <<= 1) {
        int u = __shfl_up(s, st);
        if (lane >= st) s += u;
    }
    int wtot = __shfl(s, 63);
    int base = 0;
    if (lane == 0 && wtot > 0) base = atomicAdd(gcur, wtot);
    base = __shfl(base, 0);
    int start = base + s - v;
    if (i < N) {
        ebase[i] = start;
        cur[i] = start;
    }
}

__global__ void claim_all(const int* ideg1, int N1, int* g1, int* eb1, int* cur1,
                          const int* ideg2, int N2, int* g2, int* eb2, int* cur2,
                          const int* ideg3, int N3, int* g3, int* eb3, int* cur3,
                          const int* ideg4, int N4, int* g4, int* eb4, int* cur4,
                          const int* ideg5, int N5, int* g5, int* eb5, int* cur5,
                          const int* h2, int* bs2, int* cu2, int* tk2, int* tl2, int* nt2,
                          const int* h3, int* bs3, int* cu3, int* tk3, int* tl3, int* nt3,
                          const int* h4, int* bs4, int* cu4, int* tk4, int* tl4, int* nt4,
                          const int* h5, int* bs5, int* cu5, int* tk5, int* tl5, int* nt5,
                          int C1, int C12, int C123, int C1234, int C12345) {
    int b = blockIdx.x, t = threadIdx.x;
    if (b < C1) { claim_seg(ideg1, N1, g1, eb1, cur1, b, t); return; }
    if (b < C12) { claim_seg(ideg2, N2, g2, eb2, cur2, b - C1, t); return; }
    if (b < C123) { claim_seg(ideg3, N3, g3, eb3, cur3, b - C12, t); return; }
    if (b < C1234) { claim_seg(ideg4, N4, g4, eb4, cur4, b - C123, t); return; }
    if (b < C12345) { claim_seg(ideg5, N5, g5, eb5, cur5, b - C1234, t); return; }
    int s = b - C12345;
    const int* hist;
    int *bs, *cu, *tk, *tl, *ntp;
    int TMv = (s == 3) ? 32 : 64;  // L2/L3/L4 TM=64, L5 TM=32
    if (s == 0) { hist = h2; bs = bs2; cu = cu2; tk = tk2; tl = tl2; ntp = nt2; }
    else if (s == 1) { hist = h3; bs = bs3; cu = cu3; tk = tk3; tl = tl3; ntp = nt3; }
    else if (s == 2) { hist = h4; bs = bs4; cu = cu4; tk = tk4; tl = tl4; ntp = nt4; }
    else { hist = h5; bs = bs5; cu = cu5; tk = tk5; tl = tl5; ntp = nt5; }
    int lane = t & 63, wv = t >> 6;
    int h = 0, th = 0;
    if (t < 125) {
        h = hist[t];
        th = (h + TMv - 1) / TMv;
    }
    unsigned long long v = (unsigned long long)(unsigned)h |
                           ((unsigned long long)(unsigned)th << 32);
#pragma unroll
    for (int st = 1; st < 64; st <<= 1) {
        unsigned long long u = __shfl_up(v, st);
        if (lane >= st) v += u;
    }
    __shared__ unsigned long long wtot[4];
    if (lane == 63) wtot[wv] = v;
    __syncthreads();
    unsigned long long woff = 0;
    for (int w2 = 0; w2 < wv; ++w2) woff += wtot[w2];
    unsigned long long incl = v + woff;
    int eh = (int)(incl & 0xFFFFFFFFull) - h;
    int eth = (int)(incl >> 32) - th;
    if (t < 125) {
        bs[t] = eh;
        cu[t] = eh;
        for (int j = 0; j < th; ++j) {
            tk[eth + j] = t;
            tl[eth + j] = eh + TMv * j;
        }
    }
    if (t == 124) {
        bs[125] = eh + h;
        *ntp = eth + th;
    }
}

// ---------------- batched scatter: L1 payloads + L2-5 edge records -----------
DEVINL void scat_seg(const float* __restrict__ ps, const int* __restrict__ src,
                     const int* __restrict__ dst, int E, int* __restrict__ cursor,
                     int* __restrict__ entcur, uint4* __restrict__ rec, int* __restrict__ sq,
                     int bofs, int t, int* __restrict__ lh, int* __restrict__ lbase) {
    for (int i = t; i < 125; i += 256) lh[i] = 0;
    __syncthreads();
    int e = bofs * 256 + t;
    int cid = 0, ml = 0;
    int ff[3];
    float fr[3];
    if (e < E) {
        pseudo_decode(ps, e, ff, fr);
        cid = ff[0] + 5 * ff[1] + 25 * ff[2];
        ml = atomicAdd(&lh[cid], 1);
    }
    __syncthreads();
    for (int i = t; i < 125; i += 256) {
        int c = lh[i];
        lbase[i] = c ? atomicAdd(&cursor[i], c) : 0;
    }
    __syncthreads();
    if (e < E) {
        int p = lbase[cid] + ml;
        int q = atomicAdd(&entcur[dst[e]], 1);
        uint4 v;
        v.x = (unsigned)src[e];
        v.y = __float_as_uint(fr[0]);
        v.z = __float_as_uint(fr[1]);
        v.w = __float_as_uint(fr[2]);
        rec[p] = v;
        sq[p] = q;
    }
}

__global__ void scatter_all(
    const int* dst1, const int* src1, const float* ps1, int E1, int* ecur1, uint4* psrc,
    const float* ps2, const int* src2, const int* dst2, int E2, int* cu2, int* entc2,
    uint4* rec2, int* sq2, const float* ps3, const int* src3, const int* dst3, int E3, int* cu3,
    int* entc3, uint4* rec3, int* sq3, const float* ps4, const int* src4, const int* dst4,
    int E4, int* cu4, int* entc4, uint4* rec4, int* sq4, const float* ps5, const int* src5,
    const int* dst5, int E5, int* cu5, int* entc5, uint4* rec5, int* sq5, int A1, int A12,
    int A123, int A1234) {
    __shared__ int lh[125], lbase[125];
    int b = blockIdx.x, t = threadIdx.x;
    if (b < A1) {
        int e = b * 256 + t;
        if (e < E1) {
            int q = atomicAdd(&ecur1[dst1[e]], 1);
            uint4 v;
            v.x = __float_as_uint(ps1[(size_t)e * 3 + 0]);
            v.y = __float_as_uint(ps1[(size_t)e * 3 + 1]);
            v.z = __float_as_uint(ps1[(size_t)e * 3 + 2]);
            v.w = (unsigned)src1[e];
            psrc[q] = v;
        }
    } else if (b < A12)
        scat_seg(ps2, src2, dst2, E2, cu2, entc2, rec2, sq2, b - A1, t, lh, lbase);
    else if (b < A123)
        scat_seg(ps3, src3, dst3, E3, cu3, entc3, rec3, sq3, b - A12, t, lh, lbase);
    else if (b < A1234)
        scat_seg(ps4, src4, dst4, E4, cu4, entc4, rec4, sq4, b - A123, t, lh, lbase);
    else
        scat_seg(ps5, src5, dst5, E5, cu5, entc5, rec5, sq5, b - A1234, t, lh, lbase);
}

// cell-binned GEMM, LDS-operand fdot2 inner loop (no per-thread arrays).
// Tile tt -> (slice c0, cell tile). xh transposed [i2][row] fp16 pairs;
// Wl [corner][i2][col] fp16 pairs; corners outer, ws applied per corner.
template <int CIN, int COUT, int S, int TM>
__global__ __launch_bounds__(256) void bin_gemm_cell(
    const unsigned* __restrict__ xm, const float* __restrict__ W, const uint4* __restrict__ rec,
    const int* __restrict__ sq, const int* __restrict__ tk, const int* __restrict__ tl,
    const int* __restrict__ bs, const int* __restrict__ ntp, unsigned* __restrict__ msgs) {
    constexpr int C4 = S / 4;       // 4-col groups per thread
    constexpr int NTR = 256 / C4;   // row-thread groups
    constexpr int RT = TM / NTR;    // rows per thread (2 or 1)
    constexpr int CIN2 = CIN / 2;   // fp16 cin-pairs
    constexpr int XT = TM + 2;      // transposed x row stride (keeps b64 align)
    constexpr int G = 256 / TM;     // threads per staged row
    __shared__ unsigned Wl[8 * CIN2 * S];  // [b][i2][c] fp16 cin-pairs
    __shared__ unsigned xh[CIN2 * XT];     // [i2][row] fp16 cin-pairs (transposed)
    __shared__ float ws[8 * TM];           // [b][row]
    __shared__ int kbs[8];
    int t = threadIdx.x;
    int ntiles = *ntp;
    int ntot = ntiles * (COUT / S);
    int tc = t % C4, tr = t / C4;
    int rr = t / G, g = t % G;
    int row0 = tr * RT;
    for (int tt = blockIdx.x; tt < ntot; tt += gridDim.x) {
        int sl = tt / ntiles;
        int tile = tt - sl * ntiles;
        int c0 = sl * S;
        int cell = tk[tile], lo = tl[tile];
        int m = min(TM, bs[cell + 1] - lo);
        __syncthreads();  // previous tile fully consumed
        if (t < 8) {
            int f0 = cell % 5, f1 = (cell / 5) % 5, f2 = cell / 25;
            int k0 = min(f0 + (t & 1), 4), k1 = min(f1 + ((t >> 1) & 1), 4),
                k2 = min(f2 + (t >> 2), 4);
            kbs[t] = k0 + 5 * k1 + 25 * k2;
        }
        if (rr < m) {
            uint4 rv = rec[lo + rr];
            if (g == 0) {
                float fr0 = __uint_as_float(rv.y), fr1 = __uint_as_float(rv.z),
                      fr2 = __uint_as_float(rv.w);
#pragma unroll
                for (int b = 0; b < 8; ++b)
                    ws[b * TM + rr] = ((b & 1) ? fr0 : 1.f - fr0) * ((b & 2) ? fr1 : 1.f - fr1) *
                                      ((b & 4) ? fr2 : 1.f - fr2);
            }
            const uint4* xr = (const uint4*)(xm + (size_t)rv.x * CIN);
            for (int i = g; i < CIN / 4; i += G) {
                uint4 mv = xr[i];
                xh[(2 * i) * XT + rr] =
                    (unsigned)f2h(mono2x(mv.x)) | ((unsigned)f2h(mono2x(mv.y)) << 16);
                xh[(2 * i + 1) * XT + rr] =
                    (unsigned)f2h(mono2x(mv.z)) | ((unsigned)f2h(mono2x(mv.w)) << 16);
            }
        } else if (g == 0) {
#pragma unroll
            for (int b = 0; b < 8; ++b) ws[b * TM + rr] = 0.f;
        }
        __syncthreads();  // kbs + xh + ws visible
        // stage all 8 W corner-slices as fp16 cin-pairs (uses kbs)
        for (int idx = t; idx < 8 * CIN2 * S; idx += 256) {
            int b = idx / (CIN2 * S);
            int rem = idx - b * (CIN2 * S);
            int i2 = rem / S, c = rem - i2 * S;
            const float* Wp = W + (size_t)kbs[b] * CIN * COUT + (size_t)(2 * i2) * COUT + c0 + c;
            Wl[idx] = (unsigned)f2h(Wp[0]) | ((unsigned)f2h(Wp[COUT]) << 16);
        }
        __syncthreads();  // Wl visible
        float4 acc[RT];
#pragma unroll
        for (int r = 0; r < RT; ++r) acc[r] = make_float4(0.f, 0.f, 0.f, 0.f);
#pragma unroll
        for (int b = 0; b < 8; ++b) {
            float4 t40 = make_float4(0.f, 0.f, 0.f, 0.f);
            float4 t41 = make_float4(0.f, 0.f, 0.f, 0.f);
            const unsigned* Wb = &Wl[b * CIN2 * S + 4 * tc];
            for (int i2 = 0; i2 < CIN2; ++i2) {
                uint4 wv = *(const uint4*)(Wb + i2 * S);
                if constexpr (RT == 2) {
                    uint2 xp = *(const uint2*)&xh[i2 * XT + row0];
                    t40.x = fdot2u(wv.x, xp.x, t40.x);
                    t40.y = fdot2u(wv.y, xp.x, t40.y);
                    t40.z = fdot2u(wv.z, xp.x, t40.z);
                    t40.w = fdot2u(wv.w, xp.x, t40.w);
                    t41.x = fdot2u(wv.x, xp.y, t41.x);
                    t41.y = fdot2u(wv.y, xp.y, t41.y);
                    t41.z = fdot2u(wv.z, xp.y, t41.z);
                    t41.w = fdot2u(wv.w, xp.y, t41.w);
                } else {
                    unsigned xp = xh[i2 * XT + row0];
                    t40.x = fdot2u(wv.x, xp, t40.x);
                    t40.y = fdot2u(wv.y, xp, t40.y);
                    t40.z = fdot2u(wv.z, xp, t40.z);
                    t40.w = fdot2u(wv.w, xp, t40.w);
                }
            }
            {
                float wsv = ws[b * TM + row0];
                acc[0].x += wsv * t40.x;
                acc[0].y += wsv * t40.y;
                acc[0].z += wsv * t40.z;
                acc[0].w += wsv * t40.w;
            }
            if constexpr (RT == 2) {
                float wsv = ws[b * TM + row0 + 1];
                acc[1].x += wsv * t41.x;
                acc[1].y += wsv * t41.y;
                acc[1].z += wsv * t41.z;
                acc[1].w += wsv * t41.w;
            }
        }
#pragma unroll
        for (int r = 0; r < RT; ++r) {
            int row = row0 + r;
            if (row < m) {
                int q = sq[lo + row];
                uint2 pv;
                pv.x = (unsigned)f2h(acc[r].x) | ((unsigned)f2h(acc[r].y) << 16);
                pv.y = (unsigned)f2h(acc[r].z) | ((unsigned)f2h(acc[r].w) << 16);
                ((uint2*)(msgs + (size_t)q * (COUT / 2)))[c0 / 4 + tc] = pv;
            }
        }
    }
}

// wave per node: contiguous claimed-range message stream (1 row per EDGE),
// butterfly reduce, deg-norm + root + bias + ELU, pool into next mono buffer.
template <int CIN, int COUT, int S>
__global__ __launch_bounds__(256) void agg_finish(
    const unsigned* __restrict__ msgsU, const int* __restrict__ ebase,
    const int* __restrict__ ideg, const unsigned* __restrict__ xm,
    const float* __restrict__ root, const float* __restrict__ bias,
    const int* __restrict__ clnext, unsigned* __restrict__ xnext, int N, int c0) {
    const unsigned short* msgs = (const unsigned short*)msgsU;
    constexpr int WPC = S / 4;
    constexpr int G = 64 / WPC;
    int t = threadIdx.x;
    int lane = t & 63;
    int wid = blockIdx.x * 4 + (t >> 6);
    int nw = gridDim.x * 4;
    int grp = lane & (WPC - 1);
    int sub = lane / WPC;
    for (int d = wid; d < N; d += nw) {
        int lo = ebase[d];
        int len = ideg[d];
        float dv = (float)max(len, 1);
        float4 acc = make_float4(0.f, 0.f, 0.f, 0.f);
        const float* rbase = root + c0 + 4 * grp;
        for (int i = sub; i < CIN; i += G) {
            float xv = mono2x(xm[(size_t)d * CIN + i]) * dv;
            const float* rp = rbase + (size_t)i * COUT;
            acc.x += xv * rp[0];
            acc.y += xv * rp[1];
            acc.z += xv * rp[2];
            acc.w += xv * rp[3];
        }
        size_t h1 = (size_t)(lo + len) * S;
        for (size_t h = (size_t)lo * S + (size_t)lane * 4; h < h1; h += 256) {
            uint2 u = *(const uint2*)(msgs + h);
            acc.x += h2f((unsigned short)(u.x & 0xFFFFu));
            acc.y += h2f((unsigned short)(u.x >> 16));
            acc.z += h2f((unsigned short)(u.y & 0xFFFFu));
            acc.w += h2f((unsigned short)(u.y >> 16));
        }
#pragma unroll
        for (int s = WPC; s < 64; s <<= 1) {
            acc.x += __shfl_xor(acc.x, s);
            acc.y += __shfl_xor(acc.y, s);
            acc.z += __shfl_xor(acc.z, s);
            acc.w += __shfl_xor(acc.w, s);
        }
        if (lane < WPC) {
            const float* bp = bias + c0 + 4 * grp;
            float4 v;
            v.x = acc.x / dv + bp[0];
            v.y = acc.y / dv + bp[1];
            v.z = acc.z / dv + bp[2];
            v.w = acc.w / dv + bp[3];
            v.x = v.x > 0.f ? v.x : expm1f(v.x);
            v.y = v.y > 0.f ? v.y : expm1f(v.y);
            v.z = v.z > 0.f ? v.z : expm1f(v.z);
            v.w = v.w > 0.f ? v.w : expm1f(v.w);
            unsigned* xp = xnext + (size_t)clnext[d] * COUT + c0 + 4 * grp;
            atomicMax(&xp[0], f2mono(v.x));
            atomicMax(&xp[1], f2mono(v.y));
            atomicMax(&xp[2], f2mono(v.z));
            atomicMax(&xp[3], f2mono(v.w));
        }
    }
}

// ---------------- level 1 (Cin=1, Cout=32): fused conv + pool into xp2m -------
__global__ __launch_bounds__(256) void l1_aggregate(
    const unsigned* __restrict__ xm, const uint4* __restrict__ psrc,
    const float* __restrict__ W, const int* __restrict__ ebase, const int* __restrict__ ideg,
    const float* __restrict__ root, const float* __restrict__ bias,
    const int* __restrict__ cl2, unsigned* __restrict__ xp2m, int N) {
    __shared__ float Wl[125 * 32];
    int t = threadIdx.x;
    {
        const float4* Wg = (const float4*)W;
        float4* Wd = (float4*)Wl;
        for (int i = t; i < 125 * 32 / 4; i += 256) Wd[i] = Wg[i];
    }
    __syncthreads();
    int lane = t & 63, c = lane & 31, half = lane >> 5;
    int wid = blockIdx.x * 4 + (t >> 6);
    int nw = gridDim.x * 4;
    for (int d = wid; d < N; d += nw) {
        int lo = ebase[d], hi = lo + ideg[d];
        float acc = 0.f;
        for (int j = lo + half; j < hi; j += 2) {
            uint4 pv = psrc[j];
            int ff[3];
            float fr[3];
            decode3(__uint_as_float(pv.x), __uint_as_float(pv.y), __uint_as_float(pv.z), ff, fr);
            float wsum = 0.f;
#pragma unroll
            for (int b = 0; b < 8; ++b) {
                float w;
                int idx;
                corner_iw(ff, fr, b, w, idx);
                wsum += w * Wl[idx * 32 + c];
            }
            acc += mono2x(xm[pv.w]) * wsum;
        }
        acc += __shfl_down(acc, 32);
        if (half == 0) {
            float dv = (float)max(hi - lo, 1);
            float v = acc / dv + mono2x(xm[d]) * root[c] + bias[c];
            v = v > 0.f ? v : expm1f(v);
            atomicMax(&xp2m[(size_t)cl2[d] * 32 + c], f2mono(v));
        }
    }
}

// fc1: [1024] @ [1024,512] + b, ELU — K-split across 8 blocks x 256 threads
__global__ __launch_bounds__(256) void fc1_kernel(const unsigned* __restrict__ xm,
                                                  const float* __restrict__ w,
                                                  const float* __restrict__ b,
                                                  float* __restrict__ out) {
    __shared__ float xsh[1024];
    __shared__ float sh[4][64];
    int t = threadIdx.x;
    for (int i = t; i < 1024; i += 256) xsh[i] = mono2x(xm[i]);
    __syncthreads();
    int ol = t & 63, kk = t >> 6;
    int o = blockIdx.x * 64 + ol;
    int i0 = kk * 256;
    float acc = 0.f;
#pragma unroll 8
    for (int i = 0; i < 256; ++i) acc += xsh[i0 + i] * w[(size_t)(i0 + i) * 512 + o];
    sh[kk][ol] = acc;
    __syncthreads();
    if (kk == 0) {
        float v = sh[0][ol] + sh[1][ol] + sh[2][ol] + sh[3][ol] + b[o];
        out[o] = v > 0.f ? v : expm1f(v);
    }
}

// fc2 (512->10) + log_softmax, parallel: thread i owns row i
__global__ __launch_bounds__(512) void fc2_lsm(const float* __restrict__ x,
                                               const float* __restrict__ w,
                                               const float* __restrict__ b,
                                               float* __restrict__ out) {
    __shared__ float red[8][10];
    int t = threadIdx.x, lane = t & 63, wv = t >> 6;
    float xv = x[t];
    const float* wr = w + (size_t)t * 10;
    float acc[10];
#pragma unroll
    for (int c = 0; c < 10; ++c) acc[c] = xv * wr[c];
#pragma unroll
    for (int s = 32; s > 0; s >>= 1) {
#pragma unroll
        for (int c = 0; c < 10; ++c) acc[c] += __shfl_down(acc[c], s);
    }
    if (lane == 0) {
#pragma unroll
        for (int c = 0; c < 10; ++c) red[wv][c] = acc[c];
    }
    __syncthreads();
    if (t == 0) {
        float z[10];
        for (int c = 0; c < 10; ++c) {
            float s2 = b[c];
            for (int w2 = 0; w2 < 8; ++w2) s2 += red[w2][c];
            z[c] = s2;
        }
        float m = z[0];
        for (int i = 1; i < 10; ++i) m = fmaxf(m, z[i]);
        float s2 = 0.f;
        for (int i = 0; i < 10; ++i) s2 += expf(z[i] - m);
        float l = logf(s2);
        for (int i = 0; i < 10; ++i) out[i] = z[i] - m - l;
    }
}

// ---------------------------------------------------------------------------

extern "C" void kernel_launch(void* const* d_in, const int* in_sizes, int n_in,
                              void* d_out, int out_size, void* d_ws, size_t ws_size,
                              hipStream_t stream) {
    (void)in_sizes; (void)n_in; (void)out_size; (void)ws_size;
    const float* x0 = (const float*)d_in[0];
    const int* cl[6];
    for (int i = 0; i < 6; ++i) cl[i] = (const int*)d_in[1 + i];
    const int* src[5];
    const int* dst[5];
    const float* ps[5];
    const float* W[5];
    const float* root[5];
    const float* bias[5];
    for (int i = 0; i < 5; ++i) {
        src[i] = (const int*)d_in[7 + 6 * i];
        dst[i] = (const int*)d_in[8 + 6 * i];
        ps[i] = (const float*)d_in[9 + 6 * i];
        W[i] = (const float*)d_in[10 + 6 * i];
        root[i] = (const float*)d_in[11 + 6 * i];
        bias[i] = (const float*)d_in[12 + 6 * i];
    }
    const float* fc1_w = (const float*)d_in[37];
    const float* fc1_b = (const float*)d_in[38];
    const float* fc2_w = (const float*)d_in[39];
    const float* fc2_b = (const float*)d_in[40];

    const int N1 = 20000, N2 = 6000, N3 = 2000, N4 = 700, N5 = 256;
    const int E1 = 160000, E2 = 48000, E3 = 16000, E4 = 5600, E5 = 2048;
    const int UB2 = E2 / 64 + 126, UB3 = E3 / 64 + 126, UB4 = E4 / 64 + 126,
              UB5 = E5 / 32 + 126;

    unsigned* base = (unsigned*)d_ws;
    size_t o = 0;
    auto alloc = [&](size_t n) { unsigned* p = base + o; o += n; return p; };
    // ---- zero block (single fill) ----
    unsigned* xp1m = alloc(N1);
    unsigned* xp2m = alloc((size_t)N2 * 32);
    unsigned* xp3m = alloc((size_t)N3 * 64);
    unsigned* xp4m = alloc((size_t)N4 * 64);
    unsigned* xp5m = alloc((size_t)N5 * 64);
    unsigned* xp6m = alloc(8 * 128);
    int* hist2 = (int*)alloc(125);
    int* hist3 = (int*)alloc(125);
    int* hist4 = (int*)alloc(125);
    int* hist5 = (int*)alloc(125);
    int* ideg1 = (int*)alloc(N1);
    int* ideg2 = (int*)alloc(N2);
    int* ideg3 = (int*)alloc(N3);
    int* ideg4 = (int*)alloc(N4);
    int* ideg5 = (int*)alloc(N5);
    int* gcur = (int*)alloc(5);
    size_t zero_words = o;
    // ---- non-zeroed dedicated ----
    int* eb1 = (int*)alloc(N1);
    int* eb2 = (int*)alloc(N2);
    int* eb3 = (int*)alloc(N3);
    int* eb4 = (int*)alloc(N4);
    int* eb5 = (int*)alloc(N5);
    int* ecur1 = (int*)alloc(N1);
    int* entc2 = (int*)alloc(N2);
    int* entc3 = (int*)alloc(N3);
    int* entc4 = (int*)alloc(N4);
    int* entc5 = (int*)alloc(N5);
    int* bs2 = (int*)alloc(126);
    int* bs3 = (int*)alloc(126);
    int* bs4 = (int*)alloc(126);
    int* bs5 = (int*)alloc(126);
    int* cu2 = (int*)alloc(125);
    int* cu3 = (int*)alloc(125);
    int* cu4 = (int*)alloc(125);
    int* cu5 = (int*)alloc(125);
    int* nt2 = (int*)alloc(1);
    int* nt3 = (int*)alloc(1);
    int* nt4 = (int*)alloc(1);
    int* nt5 = (int*)alloc(1);
    int* tk2 = (int*)alloc(UB2);
    int* tl2 = (int*)alloc(UB2);
    int* tk3 = (int*)alloc(UB3);
    int* tl3 = (int*)alloc(UB3);
    int* tk4 = (int*)alloc(UB4);
    int* tl4 = (int*)alloc(UB4);
    int* tk5 = (int*)alloc(UB5);
    int* tl5 = (int*)alloc(UB5);
    float* fc1o = (float*)alloc(512);
    o = (o + 3) & ~(size_t)3;  // 16B-align the uint4 region
    uint4* rec2 = (uint4*)alloc((size_t)4 * E2);
    int* sq2 = (int*)alloc(E2);
    uint4* rec3 = (uint4*)alloc((size_t)4 * E3);
    int* sq3 = (int*)alloc(E3);
    uint4* rec4 = (uint4*)alloc((size_t)4 * E4);
    int* sq4 = (int*)alloc(E4);
    uint4* rec5 = (uint4*)alloc((size_t)4 * E5);
    int* sq5 = (int*)alloc(E5);
    uint4* psrc = (uint4*)alloc((size_t)4 * E1);
    unsigned* msgs = alloc((size_t)E2 * 32);  // max of E_L * COUT/2 across levels

    // ---- 1. one fill for monos + hists + idegs + cursors ----
    fill_u32<<<((int)zero_words + 255) / 256, 256, 0, stream>>>(base, (int)zero_words, 0u);

    // ---- 2. batched hist/deg + pool0 ----
    int nb2 = (E2 + 255) / 256, nb3 = (E3 + 255) / 256, nb4 = (E4 + 255) / 256,
        nb5 = (E5 + 255) / 256, nb1 = (E1 + 255) / 256, nb0 = (80000 + 255) / 256;
    int B2 = nb2, B23 = B2 + nb3, B234 = B23 + nb4, B2345 = B234 + nb5;
    int B1end = B2345 + nb1;
    hist_all<<<B1end + nb0, 256, 0, stream>>>(ps[1], dst[1], E2, hist2, ideg2, ps[2], dst[2], E3,
                                              hist3, ideg3, ps[3], dst[3], E4, hist4, ideg4,
                                              ps[4], dst[4], E5, hist5, ideg5, dst[0], E1, ideg1,
                                              x0, cl[0], 80000, xp1m, B2, B23, B234, B2345,
                                              B1end);

    // ---- 3. claims + bin prefixes ----
    int nc1 = (N1 + 255) / 256, nc2 = (N2 + 255) / 256, nc3 = (N3 + 255) / 256,
        nc4 = (N4 + 255) / 256, nc5 = (N5 + 255) / 256;
    int C1 = nc1, C12 = C1 + nc2, C123 = C12 + nc3, C1234 = C123 + nc4, C12345 = C1234 + nc5;
    claim_all<<<C12345 + 4, 256, 0, stream>>>(
        ideg1, N1, gcur + 0, eb1, ecur1, ideg2, N2, gcur + 1, eb2, entc2, ideg3, N3, gcur + 2,
        eb3, entc3, ideg4, N4, gcur + 3, eb4, entc4, ideg5, N5, gcur + 4, eb5, entc5, hist2, bs2,
        cu2, tk2, tl2, nt2, hist3, bs3, cu3, tk3, tl3, nt3, hist4, bs4, cu4, tk4, tl4, nt4,
        hist5, bs5, cu5, tk5, tl5, nt5, C1, C12, C123, C1234, C12345);

    // ---- 4. all scatters in one dispatch ----
    int A1 = nb1, A12 = A1 + nb2, A123 = A12 + nb3, A1234 = A123 + nb4;
    scatter_all<<<A1234 + nb5, 256, 0, stream>>>(
        dst[0], src[0], ps[0], E1, ecur1, psrc, ps[1], src[1], dst[1], E2, cu2, entc2, rec2, sq2,
        ps[2], src[2], dst[2], E3, cu3, entc3, rec3, sq3, ps[3], src[3], dst[3], E4, cu4, entc4,
        rec4, sq4, ps[4], src[4], dst[4], E5, cu5, entc5, rec5, sq5, A1, A12, A123, A1234);

    // ---- level 1 ----
    l1_aggregate<<<2048, 256, 0, stream>>>(xp1m, psrc, W[0], eb1, ideg1, root[0], bias[0], cl[1],
                                           xp2m, N1);
    // ---- level 2: Cin32 Cout64, S=32 slices ----
    bin_gemm_cell<32, 64, 32, 64><<<(2 * UB2 < 2048 ? 2 * UB2 : 2048), 256, 0, stream>>>(
        xp2m, W[1], rec2, sq2, tk2, tl2, bs2, nt2, msgs);
    agg_finish<32, 64, 64><<<(N2 + 3) / 4, 256, 0, stream>>>(msgs, eb2, ideg2, xp2m, root[1],
                                                             bias[1], cl[2], xp3m, N2, 0);
    // ---- level 3: Cin64 Cout64, S=32 slices ----
    bin_gemm_cell<64, 64, 32, 64><<<(2 * UB3 < 2048 ? 2 * UB3 : 2048), 256, 0, stream>>>(
        xp3m, W[2], rec3, sq3, tk3, tl3, bs3, nt3, msgs);
    agg_finish<64, 64, 64><<<(N3 + 3) / 4, 256, 0, stream>>>(msgs, eb3, ideg3, xp3m, root[2],
                                                             bias[2], cl[3], xp4m, N3, 0);
    // ---- level 4: Cin64 Cout64, S=32 slices ----
    bin_gemm_cell<64, 64, 32, 64><<<(2 * UB4 < 2048 ? 2 * UB4 : 2048), 256, 0, stream>>>(
        xp4m, W[3], rec4, sq4, tk4, tl4, bs4, nt4, msgs);
    agg_finish<64, 64, 64><<<(N4 + 3) / 4, 256, 0, stream>>>(msgs, eb4, ideg4, xp4m, root[3],
                                                             bias[3], cl[4], xp5m, N4, 0);
    // ---- level 5: Cin64 Cout128, S=32 slices (4x) ----
    bin_gemm_cell<64, 128, 32, 32><<<(4 * UB5 < 2048 ? 4 * UB5 : 2048), 256, 0, stream>>>(
        xp5m, W[4], rec5, sq5, tk5, tl5, bs5, nt5, msgs);
    agg_finish<64, 128, 128><<<(N5 + 3) / 4, 256, 0, stream>>>(msgs, eb5, ideg5, xp5m, root[4],
                                                               bias[4], cl[5], xp6m, N5, 0);
    // ---- FC head ----
    fc1_kernel<<<8, 256, 0, stream>>>(xp6m, fc1_w, fc1_b, fc1o);
    fc2_lsm<<<1, 512, 0, stream>>>(fc1o, fc2_w, fc2_b, (float*)d_out);
}

// Round 13
// 215.595 us; speedup vs baseline: 4.3675x; 4.3675x over previous
//
#include <hip/hip_runtime.h>
#include <hip/hip_fp16.h>
#include <math.h>

#define DEVINL __device__ __forceinline__

// ---------------------------------------------------------------------------
// SplineCNN net, round 12: round-11 fdot2 GEMM with BOUNDED unrolling.
//  - round 11 spilled because the un-pragma'd i2 loop inside the unrolled
//    8-corner loop was fully unrolled (8*CIN2 bodies) and all ds_reads got
//    hoisted -> 256 VGPR + 470MB scratch. Fix: '#pragma unroll 1' on the
//    corner loop, '#pragma unroll 2' on i2 -> <=4 in-flight LDS loads.
//  - everything else identical to round 11 (round-8 pipeline structure).
// ---------------------------------------------------------------------------

typedef _Float16 h2t __attribute__((ext_vector_type(2)));

DEVINL unsigned f2mono(float f) {
    unsigned u = __float_as_uint(f);
    return (u & 0x80000000u) ? ~u : (u | 0x80000000u);
}
DEVINL float mono2x(unsigned m) {  // sentinel 0 == empty segment -> 0.0
    if (m == 0u) return 0.f;
    unsigned u = (m & 0x80000000u) ? (m & 0x7FFFFFFFu) : ~m;
    return __uint_as_float(u);
}
DEVINL unsigned short f2h(float f) {
    union { __half h; unsigned short u; } c;
    c.h = __float2half_rn(f);
    return c.u;
}
DEVINL float h2f(unsigned short s) {
    union { unsigned short u; __half h; } c;
    c.u = s;
    return __half2float(c.h);
}
DEVINL float fdot2u(unsigned w, unsigned x, float acc) {
    union { unsigned u; h2t h; } cw, cx;
    cw.u = w;
    cx.u = x;
    return __builtin_amdgcn_fdot2(cw.h, cx.h, acc, false);
}

__global__ void fill_u32(unsigned* __restrict__ p, int n, unsigned v) {
    int i = blockIdx.x * blockDim.x + threadIdx.x;
    if (i < n) p[i] = v;
}

DEVINL void decode3(float p0, float p1, float p2, int ff[3], float fr[3]) {
    float pp[3] = {p0 * 4.f, p1 * 4.f, p2 * 4.f};  // (K-1) = 4
#pragma unroll
    for (int d = 0; d < 3; ++d) {
        int fi = (int)floorf(pp[d]);
        fi = fi < 0 ? 0 : (fi > 4 ? 4 : fi);
        ff[d] = fi;
        fr[d] = pp[d] - (float)fi;
    }
}
DEVINL void pseudo_decode(const float* __restrict__ ps, int e, int ff[3], float fr[3]) {
    decode3(ps[(size_t)e * 3], ps[(size_t)e * 3 + 1], ps[(size_t)e * 3 + 2], ff, fr);
}

DEVINL void corner_iw(const int ff[3], const float fr[3], int bits, float& w, int& idx) {
    w = 1.f;
    idx = 0;
    int pw = 1;
#pragma unroll
    for (int d = 0; d < 3; ++d) {
        int b = (bits >> d) & 1;
        w *= b ? fr[d] : (1.f - fr[d]);
        int fd = ff[d] + b;
        fd = fd < 0 ? 0 : (fd > 4 ? 4 : fd);
        idx += fd * pw;
        pw *= 5;
    }
}

// ---------------- batched hist (cell id, L2-5) + deg (all) + pool0 -----------
DEVINL void hist_seg(const float* __restrict__ ps, const int* __restrict__ dst, int E,
                     int* __restrict__ hist, int* __restrict__ ideg, int bofs, int t,
                     int* __restrict__ lh) {
    for (int i = t; i < 125; i += 256) lh[i] = 0;
    __syncthreads();
    int e = bofs * 256 + t;
    if (e < E) {
        int ff[3];
        float fr[3];
        pseudo_decode(ps, e, ff, fr);
        int cid = ff[0] + 5 * ff[1] + 25 * ff[2];
        atomicAdd(&lh[cid], 1);
        atomicAdd(&ideg[dst[e]], 1);
    }
    __syncthreads();
    for (int i = t; i < 125; i += 256)
        if (lh[i]) atomicAdd(&hist[i], lh[i]);
}

__global__ void hist_all(const float* ps2, const int* dst2, int E2, int* hist2, int* ideg2,
                         const float* ps3, const int* dst3, int E3, int* hist3, int* ideg3,
                         const float* ps4, const int* dst4, int E4, int* hist4, int* ideg4,
                         const float* ps5, const int* dst5, int E5, int* hist5, int* ideg5,
                         const int* dst1, int E1, int* ideg1, const float* x0, const int* cl1,
                         int n0, unsigned* xp1m, int B2, int B23, int B234, int B2345,
                         int B1end) {
    __shared__ int lh[125];
    int b = blockIdx.x, t = threadIdx.x;
    if (b < B2) hist_seg(ps2, dst2, E2, hist2, ideg2, b, t, lh);
    else if (b < B23) hist_seg(ps3, dst3, E3, hist3, ideg3, b - B2, t, lh);
    else if (b < B234) hist_seg(ps4, dst4, E4, hist4, ideg4, b - B23, t, lh);
    else if (b < B2345) hist_seg(ps5, dst5, E5, hist5, ideg5, b - B234, t, lh);
    else if (b < B1end) {
        int e = (b - B2345) * 256 + t;
        if (e < E1) atomicAdd(&ideg1[dst1[e]], 1);
    } else {
        int i = (b - B1end) * 256 + t;
        if (i < n0) atomicMax(&xp1m[cl1[i]], f2mono(x0[i]));
    }
}

// ---------------- claims + bin-prefixes (wave-parallel) ----------------------
DEVINL void claim_seg(const int* __restrict__ cnt, int N, int* __restrict__ gcur,
                      int* __restrict__ ebase, int* __restrict__ cur, int bofs, int t) {
    int i = bofs * 256 + t;
    int lane = t & 63;
    int v = (i < N) ? cnt[i] : 0;
    int s = v;
#pragma unroll
    for (int st = 1; st < 64; st <<= 1) {
        int u = __shfl_up(s, st);
        if (lane >= st) s += u;
    }
    int wtot = __shfl(s, 63);
    int base = 0;
    if (lane == 0 && wtot > 0) base = atomicAdd(gcur, wtot);
    base = __shfl(base, 0);
    int start = base + s - v;
    if (i < N) {
        ebase[i] = start;
        cur[i] = start;
    }
}

__global__ void claim_all(const int* ideg1, int N1, int* g1, int* eb1, int* cur1,
                          const int* ideg2, int N2, int* g2, int* eb2, int* cur2,
                          const int* ideg3, int N3, int* g3, int* eb3, int* cur3,
                          const int* ideg4, int N4, int* g4, int* eb4, int* cur4,
                          const int* ideg5, int N5, int* g5, int* eb5, int* cur5,
                          const int* h2, int* bs2, int* cu2, int* tk2, int* tl2, int* nt2,
                          const int* h3, int* bs3, int* cu3, int* tk3, int* tl3, int* nt3,
                          const int* h4, int* bs4, int* cu4, int* tk4, int* tl4, int* nt4,
                          const int* h5, int* bs5, int* cu5, int* tk5, int* tl5, int* nt5,
                          int C1, int C12, int C123, int C1234, int C12345) {
    int b = blockIdx.x, t = threadIdx.x;
    if (b < C1) { claim_seg(ideg1, N1, g1, eb1, cur1, b, t); return; }
    if (b < C12) { claim_seg(ideg2, N2, g2, eb2, cur2, b - C1, t); return; }
    if (b < C123) { claim_seg(ideg3, N3, g3, eb3, cur3, b - C12, t); return; }
    if (b < C1234) { claim_seg(ideg4, N4, g4, eb4, cur4, b - C123, t); return; }
    if (b < C12345) { claim_seg(ideg5, N5, g5, eb5, cur5, b - C1234, t); return; }
    int s = b - C12345;
    const int* hist;
    int *bs, *cu, *tk, *tl, *ntp;
    int TMv = (s == 3) ? 32 : 64;  // L2/L3/L4 TM=64, L5 TM=32
    if (s == 0) { hist = h2; bs = bs2; cu = cu2; tk = tk2; tl = tl2; ntp = nt2; }
    else if (s == 1) { hist = h3; bs = bs3; cu = cu3; tk = tk3; tl = tl3; ntp = nt3; }
    else if (s == 2) { hist = h4; bs = bs4; cu = cu4; tk = tk4; tl = tl4; ntp = nt4; }
    else { hist = h5; bs = bs5; cu = cu5; tk = tk5; tl = tl5; ntp = nt5; }
    int lane = t & 63, wv = t >> 6;
    int h = 0, th = 0;
    if (t < 125) {
        h = hist[t];
        th = (h + TMv - 1) / TMv;
    }
    unsigned long long v = (unsigned long long)(unsigned)h |
                           ((unsigned long long)(unsigned)th << 32);
#pragma unroll
    for (int st = 1; st < 64; st <<= 1) {
        unsigned long long u = __shfl_up(v, st);
        if (lane >= st) v += u;
    }
    __shared__ unsigned long long wtot[4];
    if (lane == 63) wtot[wv] = v;
    __syncthreads();
    unsigned long long woff = 0;
    for (int w2 = 0; w2 < wv; ++w2) woff += wtot[w2];
    unsigned long long incl = v + woff;
    int eh = (int)(incl & 0xFFFFFFFFull) - h;
    int eth = (int)(incl >> 32) - th;
    if (t < 125) {
        bs[t] = eh;
        cu[t] = eh;
        for (int j = 0; j < th; ++j) {
            tk[eth + j] = t;
            tl[eth + j] = eh + TMv * j;
        }
    }
    if (t == 124) {
        bs[125] = eh + h;
        *ntp = eth + th;
    }
}

// ---------------- batched scatter: L1 payloads + L2-5 edge records -----------
DEVINL void scat_seg(const float* __restrict__ ps, const int* __restrict__ src,
                     const int* __restrict__ dst, int E, int* __restrict__ cursor,
                     int* __restrict__ entcur, uint4* __restrict__ rec, int* __restrict__ sq,
                     int bofs, int t, int* __restrict__ lh, int* __restrict__ lbase) {
    for (int i = t; i < 125; i += 256) lh[i] = 0;
    __syncthreads();
    int e = bofs * 256 + t;
    int cid = 0, ml = 0;
    int ff[3];
    float fr[3];
    if (e < E) {
        pseudo_decode(ps, e, ff, fr);
        cid = ff[0] + 5 * ff[1] + 25 * ff[2];
        ml = atomicAdd(&lh[cid], 1);
    }
    __syncthreads();
    for (int i = t; i < 125; i += 256) {
        int c = lh[i];
        lbase[i] = c ? atomicAdd(&cursor[i], c) : 0;
    }
    __syncthreads();
    if (e < E) {
        int p = lbase[cid] + ml;
        int q = atomicAdd(&entcur[dst[e]], 1);
        uint4 v;
        v.x = (unsigned)src[e];
        v.y = __float_as_uint(fr[0]);
        v.z = __float_as_uint(fr[1]);
        v.w = __float_as_uint(fr[2]);
        rec[p] = v;
        sq[p] = q;
    }
}

__global__ void scatter_all(
    const int* dst1, const int* src1, const float* ps1, int E1, int* ecur1, uint4* psrc,
    const float* ps2, const int* src2, const int* dst2, int E2, int* cu2, int* entc2,
    uint4* rec2, int* sq2, const float* ps3, const int* src3, const int* dst3, int E3, int* cu3,
    int* entc3, uint4* rec3, int* sq3, const float* ps4, const int* src4, const int* dst4,
    int E4, int* cu4, int* entc4, uint4* rec4, int* sq4, const float* ps5, const int* src5,
    const int* dst5, int E5, int* cu5, int* entc5, uint4* rec5, int* sq5, int A1, int A12,
    int A123, int A1234) {
    __shared__ int lh[125], lbase[125];
    int b = blockIdx.x, t = threadIdx.x;
    if (b < A1) {
        int e = b * 256 + t;
        if (e < E1) {
            int q = atomicAdd(&ecur1[dst1[e]], 1);
            uint4 v;
            v.x = __float_as_uint(ps1[(size_t)e * 3 + 0]);
            v.y = __float_as_uint(ps1[(size_t)e * 3 + 1]);
            v.z = __float_as_uint(ps1[(size_t)e * 3 + 2]);
            v.w = (unsigned)src1[e];
            psrc[q] = v;
        }
    } else if (b < A12)
        scat_seg(ps2, src2, dst2, E2, cu2, entc2, rec2, sq2, b - A1, t, lh, lbase);
    else if (b < A123)
        scat_seg(ps3, src3, dst3, E3, cu3, entc3, rec3, sq3, b - A12, t, lh, lbase);
    else if (b < A1234)
        scat_seg(ps4, src4, dst4, E4, cu4, entc4, rec4, sq4, b - A123, t, lh, lbase);
    else
        scat_seg(ps5, src5, dst5, E5, cu5, entc5, rec5, sq5, b - A1234, t, lh, lbase);
}

// cell-binned GEMM, LDS-operand fdot2 inner loop, BOUNDED unrolling.
template <int CIN, int COUT, int S, int TM>
__global__ __launch_bounds__(256) void bin_gemm_cell(
    const unsigned* __restrict__ xm, const float* __restrict__ W, const uint4* __restrict__ rec,
    const int* __restrict__ sq, const int* __restrict__ tk, const int* __restrict__ tl,
    const int* __restrict__ bs, const int* __restrict__ ntp, unsigned* __restrict__ msgs) {
    constexpr int C4 = S / 4;       // 4-col groups per thread
    constexpr int NTR = 256 / C4;   // row-thread groups
    constexpr int RT = TM / NTR;    // rows per thread (2 or 1)
    constexpr int CIN2 = CIN / 2;   // fp16 cin-pairs
    constexpr int XT = TM + 2;      // transposed x row stride (keeps b64 align)
    constexpr int G = 256 / TM;     // threads per staged row
    __shared__ unsigned Wl[8 * CIN2 * S];  // [b][i2][c] fp16 cin-pairs
    __shared__ unsigned xh[CIN2 * XT];     // [i2][row] fp16 cin-pairs (transposed)
    __shared__ float ws[8 * TM];           // [b][row]
    __shared__ int kbs[8];
    int t = threadIdx.x;
    int ntiles = *ntp;
    int ntot = ntiles * (COUT / S);
    int tc = t % C4, tr = t / C4;
    int rr = t / G, g = t % G;
    int row0 = tr * RT;
    for (int tt = blockIdx.x; tt < ntot; tt += gridDim.x) {
        int sl = tt / ntiles;
        int tile = tt - sl * ntiles;
        int c0 = sl * S;
        int cell = tk[tile], lo = tl[tile];
        int m = min(TM, bs[cell + 1] - lo);
        __syncthreads();  // previous tile fully consumed
        if (t < 8) {
            int f0 = cell % 5, f1 = (cell / 5) % 5, f2 = cell / 25;
            int k0 = min(f0 + (t & 1), 4), k1 = min(f1 + ((t >> 1) & 1), 4),
                k2 = min(f2 + (t >> 2), 4);
            kbs[t] = k0 + 5 * k1 + 25 * k2;
        }
        if (rr < m) {
            uint4 rv = rec[lo + rr];
            if (g == 0) {
                float fr0 = __uint_as_float(rv.y), fr1 = __uint_as_float(rv.z),
                      fr2 = __uint_as_float(rv.w);
#pragma unroll
                for (int b = 0; b < 8; ++b)
                    ws[b * TM + rr] = ((b & 1) ? fr0 : 1.f - fr0) * ((b & 2) ? fr1 : 1.f - fr1) *
                                      ((b & 4) ? fr2 : 1.f - fr2);
            }
            const uint4* xr = (const uint4*)(xm + (size_t)rv.x * CIN);
            for (int i = g; i < CIN / 4; i += G) {
                uint4 mv = xr[i];
                xh[(2 * i) * XT + rr] =
                    (unsigned)f2h(mono2x(mv.x)) | ((unsigned)f2h(mono2x(mv.y)) << 16);
                xh[(2 * i + 1) * XT + rr] =
                    (unsigned)f2h(mono2x(mv.z)) | ((unsigned)f2h(mono2x(mv.w)) << 16);
            }
        } else if (g == 0) {
#pragma unroll
            for (int b = 0; b < 8; ++b) ws[b * TM + rr] = 0.f;
        }
        __syncthreads();  // kbs + xh + ws visible
        // stage all 8 W corner-slices as fp16 cin-pairs (uses kbs)
        for (int idx = t; idx < 8 * CIN2 * S; idx += 256) {
            int b = idx / (CIN2 * S);
            int rem = idx - b * (CIN2 * S);
            int i2 = rem / S, c = rem - i2 * S;
            const float* Wp = W + (size_t)kbs[b] * CIN * COUT + (size_t)(2 * i2) * COUT + c0 + c;
            Wl[idx] = (unsigned)f2h(Wp[0]) | ((unsigned)f2h(Wp[COUT]) << 16);
        }
        __syncthreads();  // Wl visible
        float4 acc[RT];
#pragma unroll
        for (int r = 0; r < RT; ++r) acc[r] = make_float4(0.f, 0.f, 0.f, 0.f);
#pragma unroll 1  // corners SEQUENTIAL: bounds live accumulators to one corner
        for (int b = 0; b < 8; ++b) {
            float4 t40 = make_float4(0.f, 0.f, 0.f, 0.f);
            float4 t41 = make_float4(0.f, 0.f, 0.f, 0.f);
            const unsigned* Wb = &Wl[b * CIN2 * S + 4 * tc];
#pragma unroll 2  // bounds in-flight LDS loads (round 11 fully unrolled+spilt)
            for (int i2 = 0; i2 < CIN2; ++i2) {
                uint4 wv = *(const uint4*)(Wb + i2 * S);
                if constexpr (RT == 2) {
                    uint2 xp = *(const uint2*)&xh[i2 * XT + row0];
                    t40.x = fdot2u(wv.x, xp.x, t40.x);
                    t40.y = fdot2u(wv.y, xp.x, t40.y);
                    t40.z = fdot2u(wv.z, xp.x, t40.z);
                    t40.w = fdot2u(wv.w, xp.x, t40.w);
                    t41.x = fdot2u(wv.x, xp.y, t41.x);
                    t41.y = fdot2u(wv.y, xp.y, t41.y);
                    t41.z = fdot2u(wv.z, xp.y, t41.z);
                    t41.w = fdot2u(wv.w, xp.y, t41.w);
                } else {
                    unsigned xp = xh[i2 * XT + row0];
                    t40.x = fdot2u(wv.x, xp, t40.x);
                    t40.y = fdot2u(wv.y, xp, t40.y);
                    t40.z = fdot2u(wv.z, xp, t40.z);
                    t40.w = fdot2u(wv.w, xp, t40.w);
                }
            }
            {
                float wsv = ws[b * TM + row0];
                acc[0].x += wsv * t40.x;
                acc[0].y += wsv * t40.y;
                acc[0].z += wsv * t40.z;
                acc[0].w += wsv * t40.w;
            }
            if constexpr (RT == 2) {
                float wsv = ws[b * TM + row0 + 1];
                acc[1].x += wsv * t41.x;
                acc[1].y += wsv * t41.y;
                acc[1].z += wsv * t41.z;
                acc[1].w += wsv * t41.w;
            }
        }
#pragma unroll
        for (int r = 0; r < RT; ++r) {
            int row = row0 + r;
            if (row < m) {
                int q = sq[lo + row];
                uint2 pv;
                pv.x = (unsigned)f2h(acc[r].x) | ((unsigned)f2h(acc[r].y) << 16);
                pv.y = (unsigned)f2h(acc[r].z) | ((unsigned)f2h(acc[r].w) << 16);
                ((uint2*)(msgs + (size_t)q * (COUT / 2)))[c0 / 4 + tc] = pv;
            }
        }
    }
}

// wave per node: contiguous claimed-range message stream (1 row per EDGE),
// butterfly reduce, deg-norm + root + bias + ELU, pool into next mono buffer.
template <int CIN, int COUT, int S>
__global__ __launch_bounds__(256) void agg_finish(
    const unsigned* __restrict__ msgsU, const int* __restrict__ ebase,
    const int* __restrict__ ideg, const unsigned* __restrict__ xm,
    const float* __restrict__ root, const float* __restrict__ bias,
    const int* __restrict__ clnext, unsigned* __restrict__ xnext, int N, int c0) {
    const unsigned short* msgs = (const unsigned short*)msgsU;
    constexpr int WPC = S / 4;
    constexpr int G = 64 / WPC;
    int t = threadIdx.x;
    int lane = t & 63;
    int wid = blockIdx.x * 4 + (t >> 6);
    int nw = gridDim.x * 4;
    int grp = lane & (WPC - 1);
    int sub = lane / WPC;
    for (int d = wid; d < N; d += nw) {
        int lo = ebase[d];
        int len = ideg[d];
        float dv = (float)max(len, 1);
        float4 acc = make_float4(0.f, 0.f, 0.f, 0.f);
        const float* rbase = root + c0 + 4 * grp;
        for (int i = sub; i < CIN; i += G) {
            float xv = mono2x(xm[(size_t)d * CIN + i]) * dv;
            const float* rp = rbase + (size_t)i * COUT;
            acc.x += xv * rp[0];
            acc.y += xv * rp[1];
            acc.z += xv * rp[2];
            acc.w += xv * rp[3];
        }
        size_t h1 = (size_t)(lo + len) * S;
        for (size_t h = (size_t)lo * S + (size_t)lane * 4; h < h1; h += 256) {
            uint2 u = *(const uint2*)(msgs + h);
            acc.x += h2f((unsigned short)(u.x & 0xFFFFu));
            acc.y += h2f((unsigned short)(u.x >> 16));
            acc.z += h2f((unsigned short)(u.y & 0xFFFFu));
            acc.w += h2f((unsigned short)(u.y >> 16));
        }
#pragma unroll
        for (int s = WPC; s < 64; s <<= 1) {
            acc.x += __shfl_xor(acc.x, s);
            acc.y += __shfl_xor(acc.y, s);
            acc.z += __shfl_xor(acc.z, s);
            acc.w += __shfl_xor(acc.w, s);
        }
        if (lane < WPC) {
            const float* bp = bias + c0 + 4 * grp;
            float4 v;
            v.x = acc.x / dv + bp[0];
            v.y = acc.y / dv + bp[1];
            v.z = acc.z / dv + bp[2];
            v.w = acc.w / dv + bp[3];
            v.x = v.x > 0.f ? v.x : expm1f(v.x);
            v.y = v.y > 0.f ? v.y : expm1f(v.y);
            v.z = v.z > 0.f ? v.z : expm1f(v.z);
            v.w = v.w > 0.f ? v.w : expm1f(v.w);
            unsigned* xp = xnext + (size_t)clnext[d] * COUT + c0 + 4 * grp;
            atomicMax(&xp[0], f2mono(v.x));
            atomicMax(&xp[1], f2mono(v.y));
            atomicMax(&xp[2], f2mono(v.z));
            atomicMax(&xp[3], f2mono(v.w));
        }
    }
}

// ---------------- level 1 (Cin=1, Cout=32): fused conv + pool into xp2m -------
__global__ __launch_bounds__(256) void l1_aggregate(
    const unsigned* __restrict__ xm, const uint4* __restrict__ psrc,
    const float* __restrict__ W, const int* __restrict__ ebase, const int* __restrict__ ideg,
    const float* __restrict__ root, const float* __restrict__ bias,
    const int* __restrict__ cl2, unsigned* __restrict__ xp2m, int N) {
    __shared__ float Wl[125 * 32];
    int t = threadIdx.x;
    {
        const float4* Wg = (const float4*)W;
        float4* Wd = (float4*)Wl;
        for (int i = t; i < 125 * 32 / 4; i += 256) Wd[i] = Wg[i];
    }
    __syncthreads();
    int lane = t & 63, c = lane & 31, half = lane >> 5;
    int wid = blockIdx.x * 4 + (t >> 6);
    int nw = gridDim.x * 4;
    for (int d = wid; d < N; d += nw) {
        int lo = ebase[d], hi = lo + ideg[d];
        float acc = 0.f;
        for (int j = lo + half; j < hi; j += 2) {
            uint4 pv = psrc[j];
            int ff[3];
            float fr[3];
            decode3(__uint_as_float(pv.x), __uint_as_float(pv.y), __uint_as_float(pv.z), ff, fr);
            float wsum = 0.f;
#pragma unroll
            for (int b = 0; b < 8; ++b) {
                float w;
                int idx;
                corner_iw(ff, fr, b, w, idx);
                wsum += w * Wl[idx * 32 + c];
            }
            acc += mono2x(xm[pv.w]) * wsum;
        }
        acc += __shfl_down(acc, 32);
        if (half == 0) {
            float dv = (float)max(hi - lo, 1);
            float v = acc / dv + mono2x(xm[d]) * root[c] + bias[c];
            v = v > 0.f ? v : expm1f(v);
            atomicMax(&xp2m[(size_t)cl2[d] * 32 + c], f2mono(v));
        }
    }
}

// fc1: [1024] @ [1024,512] + b, ELU — K-split across 8 blocks x 256 threads
__global__ __launch_bounds__(256) void fc1_kernel(const unsigned* __restrict__ xm,
                                                  const float* __restrict__ w,
                                                  const float* __restrict__ b,
                                                  float* __restrict__ out) {
    __shared__ float xsh[1024];
    __shared__ float sh[4][64];
    int t = threadIdx.x;
    for (int i = t; i < 1024; i += 256) xsh[i] = mono2x(xm[i]);
    __syncthreads();
    int ol = t & 63, kk = t >> 6;
    int o = blockIdx.x * 64 + ol;
    int i0 = kk * 256;
    float acc = 0.f;
#pragma unroll 8
    for (int i = 0; i < 256; ++i) acc += xsh[i0 + i] * w[(size_t)(i0 + i) * 512 + o];
    sh[kk][ol] = acc;
    __syncthreads();
    if (kk == 0) {
        float v = sh[0][ol] + sh[1][ol] + sh[2][ol] + sh[3][ol] + b[o];
        out[o] = v > 0.f ? v : expm1f(v);
    }
}

// fc2 (512->10) + log_softmax, parallel: thread i owns row i
__global__ __launch_bounds__(512) void fc2_lsm(const float* __restrict__ x,
                                               const float* __restrict__ w,
                                               const float* __restrict__ b,
                                               float* __restrict__ out) {
    __shared__ float red[8][10];
    int t = threadIdx.x, lane = t & 63, wv = t >> 6;
    float xv = x[t];
    const float* wr = w + (size_t)t * 10;
    float acc[10];
#pragma unroll
    for (int c = 0; c < 10; ++c) acc[c] = xv * wr[c];
#pragma unroll
    for (int s = 32; s > 0; s >>= 1) {
#pragma unroll
        for (int c = 0; c < 10; ++c) acc[c] += __shfl_down(acc[c], s);
    }
    if (lane == 0) {
#pragma unroll
        for (int c = 0; c < 10; ++c) red[wv][c] = acc[c];
    }
    __syncthreads();
    if (t == 0) {
        float z[10];
        for (int c = 0; c < 10; ++c) {
            float s2 = b[c];
            for (int w2 = 0; w2 < 8; ++w2) s2 += red[w2][c];
            z[c] = s2;
        }
        float m = z[0];
        for (int i = 1; i < 10; ++i) m = fmaxf(m, z[i]);
        float s2 = 0.f;
        for (int i = 0; i < 10; ++i) s2 += expf(z[i] - m);
        float l = logf(s2);
        for (int i = 0; i < 10; ++i) out[i] = z[i] - m - l;
    }
}

// ---------------------------------------------------------------------------

extern "C" void kernel_launch(void* const* d_in, const int* in_sizes, int n_in,
                              void* d_out, int out_size, void* d_ws, size_t ws_size,
                              hipStream_t stream) {
    (void)in_sizes; (void)n_in; (void)out_size; (void)ws_size;
    const float* x0 = (const float*)d_in[0];
    const int* cl[6];
    for (int i = 0; i < 6; ++i) cl[i] = (const int*)d_in[1 + i];
    const int* src[5];
    const int* dst[5];
    const float* ps[5];
    const float* W[5];
    const float* root[5];
    const float* bias[5];
    for (int i = 0; i < 5; ++i) {
        src[i] = (const int*)d_in[7 + 6 * i];
        dst[i] = (const int*)d_in[8 + 6 * i];
        ps[i] = (const float*)d_in[9 + 6 * i];
        W[i] = (const float*)d_in[10 + 6 * i];
        root[i] = (const float*)d_in[11 + 6 * i];
        bias[i] = (const float*)d_in[12 + 6 * i];
    }
    const float* fc1_w = (const float*)d_in[37];
    const float* fc1_b = (const float*)d_in[38];
    const float* fc2_w = (const float*)d_in[39];
    const float* fc2_b = (const float*)d_in[40];

    const int N1 = 20000, N2 = 6000, N3 = 2000, N4 = 700, N5 = 256;
    const int E1 = 160000, E2 = 48000, E3 = 16000, E4 = 5600, E5 = 2048;
    const int UB2 = E2 / 64 + 126, UB3 = E3 / 64 + 126, UB4 = E4 / 64 + 126,
              UB5 = E5 / 32 + 126;

    unsigned* base = (unsigned*)d_ws;
    size_t o = 0;
    auto alloc = [&](size_t n) { unsigned* p = base + o; o += n; return p; };
    // ---- zero block (single fill) ----
    unsigned* xp1m = alloc(N1);
    unsigned* xp2m = alloc((size_t)N2 * 32);
    unsigned* xp3m = alloc((size_t)N3 * 64);
    unsigned* xp4m = alloc((size_t)N4 * 64);
    unsigned* xp5m = alloc((size_t)N5 * 64);
    unsigned* xp6m = alloc(8 * 128);
    int* hist2 = (int*)alloc(125);
    int* hist3 = (int*)alloc(125);
    int* hist4 = (int*)alloc(125);
    int* hist5 = (int*)alloc(125);
    int* ideg1 = (int*)alloc(N1);
    int* ideg2 = (int*)alloc(N2);
    int* ideg3 = (int*)alloc(N3);
    int* ideg4 = (int*)alloc(N4);
    int* ideg5 = (int*)alloc(N5);
    int* gcur = (int*)alloc(5);
    size_t zero_words = o;
    // ---- non-zeroed dedicated ----
    int* eb1 = (int*)alloc(N1);
    int* eb2 = (int*)alloc(N2);
    int* eb3 = (int*)alloc(N3);
    int* eb4 = (int*)alloc(N4);
    int* eb5 = (int*)alloc(N5);
    int* ecur1 = (int*)alloc(N1);
    int* entc2 = (int*)alloc(N2);
    int* entc3 = (int*)alloc(N3);
    int* entc4 = (int*)alloc(N4);
    int* entc5 = (int*)alloc(N5);
    int* bs2 = (int*)alloc(126);
    int* bs3 = (int*)alloc(126);
    int* bs4 = (int*)alloc(126);
    int* bs5 = (int*)alloc(126);
    int* cu2 = (int*)alloc(125);
    int* cu3 = (int*)alloc(125);
    int* cu4 = (int*)alloc(125);
    int* cu5 = (int*)alloc(125);
    int* nt2 = (int*)alloc(1);
    int* nt3 = (int*)alloc(1);
    int* nt4 = (int*)alloc(1);
    int* nt5 = (int*)alloc(1);
    int* tk2 = (int*)alloc(UB2);
    int* tl2 = (int*)alloc(UB2);
    int* tk3 = (int*)alloc(UB3);
    int* tl3 = (int*)alloc(UB3);
    int* tk4 = (int*)alloc(UB4);
    int* tl4 = (int*)alloc(UB4);
    int* tk5 = (int*)alloc(UB5);
    int* tl5 = (int*)alloc(UB5);
    float* fc1o = (float*)alloc(512);
    o = (o + 3) & ~(size_t)3;  // 16B-align the uint4 region
    uint4* rec2 = (uint4*)alloc((size_t)4 * E2);
    int* sq2 = (int*)alloc(E2);
    uint4* rec3 = (uint4*)alloc((size_t)4 * E3);
    int* sq3 = (int*)alloc(E3);
    uint4* rec4 = (uint4*)alloc((size_t)4 * E4);
    int* sq4 = (int*)alloc(E4);
    uint4* rec5 = (uint4*)alloc((size_t)4 * E5);
    int* sq5 = (int*)alloc(E5);
    uint4* psrc = (uint4*)alloc((size_t)4 * E1);
    unsigned* msgs = alloc((size_t)E2 * 32);  // max of E_L * COUT/2 across levels

    // ---- 1. one fill for monos + hists + idegs + cursors ----
    fill_u32<<<((int)zero_words + 255) / 256, 256, 0, stream>>>(base, (int)zero_words, 0u);

    // ---- 2. batched hist/deg + pool0 ----
    int nb2 = (E2 + 255) / 256, nb3 = (E3 + 255) / 256, nb4 = (E4 + 255) / 256,
        nb5 = (E5 + 255) / 256, nb1 = (E1 + 255) / 256, nb0 = (80000 + 255) / 256;
    int B2 = nb2, B23 = B2 + nb3, B234 = B23 + nb4, B2345 = B234 + nb5;
    int B1end = B2345 + nb1;
    hist_all<<<B1end + nb0, 256, 0, stream>>>(ps[1], dst[1], E2, hist2, ideg2, ps[2], dst[2], E3,
                                              hist3, ideg3, ps[3], dst[3], E4, hist4, ideg4,
                                              ps[4], dst[4], E5, hist5, ideg5, dst[0], E1, ideg1,
                                              x0, cl[0], 80000, xp1m, B2, B23, B234, B2345,
                                              B1end);

    // ---- 3. claims + bin prefixes ----
    int nc1 = (N1 + 255) / 256, nc2 = (N2 + 255) / 256, nc3 = (N3 + 255) / 256,
        nc4 = (N4 + 255) / 256, nc5 = (N5 + 255) / 256;
    int C1 = nc1, C12 = C1 + nc2, C123 = C12 + nc3, C1234 = C123 + nc4, C12345 = C1234 + nc5;
    claim_all<<<C12345 + 4, 256, 0, stream>>>(
        ideg1, N1, gcur + 0, eb1, ecur1, ideg2, N2, gcur + 1, eb2, entc2, ideg3, N3, gcur + 2,
        eb3, entc3, ideg4, N4, gcur + 3, eb4, entc4, ideg5, N5, gcur + 4, eb5, entc5, hist2, bs2,
        cu2, tk2, tl2, nt2, hist3, bs3, cu3, tk3, tl3, nt3, hist4, bs4, cu4, tk4, tl4, nt4,
        hist5, bs5, cu5, tk5, tl5, nt5, C1, C12, C123, C1234, C12345);

    // ---- 4. all scatters in one dispatch ----
    int A1 = nb1, A12 = A1 + nb2, A123 = A12 + nb3, A1234 = A123 + nb4;
    scatter_all<<<A1234 + nb5, 256, 0, stream>>>(
        dst[0], src[0], ps[0], E1, ecur1, psrc, ps[1], src[1], dst[1], E2, cu2, entc2, rec2, sq2,
        ps[2], src[2], dst[2], E3, cu3, entc3, rec3, sq3, ps[3], src[3], dst[3], E4, cu4, entc4,
        rec4, sq4, ps[4], src[4], dst[4], E5, cu5, entc5, rec5, sq5, A1, A12, A123, A1234);

    // ---- level 1 ----
    l1_aggregate<<<2048, 256, 0, stream>>>(xp1m, psrc, W[0], eb1, ideg1, root[0], bias[0], cl[1],
                                           xp2m, N1);
    // ---- level 2: Cin32 Cout64, S=32 slices ----
    bin_gemm_cell<32, 64, 32, 64><<<(2 * UB2 < 2048 ? 2 * UB2 : 2048), 256, 0, stream>>>(
        xp2m, W[1], rec2, sq2, tk2, tl2, bs2, nt2, msgs);
    agg_finish<32, 64, 64><<<(N2 + 3) / 4, 256, 0, stream>>>(msgs, eb2, ideg2, xp2m, root[1],
                                                             bias[1], cl[2], xp3m, N2, 0);
    // ---- level 3: Cin64 Cout64, S=32 slices ----
    bin_gemm_cell<64, 64, 32, 64><<<(2 * UB3 < 2048 ? 2 * UB3 : 2048), 256, 0, stream>>>(
        xp3m, W[2], rec3, sq3, tk3, tl3, bs3, nt3, msgs);
    agg_finish<64, 64, 64><<<(N3 + 3) / 4, 256, 0, stream>>>(msgs, eb3, ideg3, xp3m, root[2],
                                                             bias[2], cl[3], xp4m, N3, 0);
    // ---- level 4: Cin64 Cout64, S=32 slices ----
    bin_gemm_cell<64, 64, 32, 64><<<(2 * UB4 < 2048 ? 2 * UB4 : 2048), 256, 0, stream>>>(
        xp4m, W[3], rec4, sq4, tk4, tl4, bs4, nt4, msgs);
    agg_finish<64, 64, 64><<<(N4 + 3) / 4, 256, 0, stream>>>(msgs, eb4, ideg4, xp4m, root[3],
                                                             bias[3], cl[4], xp5m, N4, 0);
    // ---- level 5: Cin64 Cout128, S=32 slices (4x) ----
    bin_gemm_cell<64, 128, 32, 32><<<(4 * UB5 < 2048 ? 4 * UB5 : 2048), 256, 0, stream>>>(
        xp5m, W[4], rec5, sq5, tk5, tl5, bs5, nt5, msgs);
    agg_finish<64, 128, 128><<<(N5 + 3) / 4, 256, 0, stream>>>(msgs, eb5, ideg5, xp5m, root[4],
                                                               bias[4], cl[5], xp6m, N5, 0);
    // ---- FC head ----
    fc1_kernel<<<8, 256, 0, stream>>>(xp6m, fc1_w, fc1_b, fc1o);
    fc2_lsm<<<1, 512, 0, stream>>>(fc1o, fc2_w, fc2_b, (float*)d_out);
}